// Round 9
// baseline (196.253 us; speedup 1.0000x reference)
//
#include <hip/hip_runtime.h>
#include <math.h>

// Problem constants (fixed by reference setup_inputs)
#define S      2048
#define DK     64
#define NBH    32            // B*H
#define QBLK   256           // q rows per block
#define NQB    (S / QBLK)    // 8 q-tiles per bh
#define NBLK   (NBH * NQB)   // 256 blocks (1/CU), 16 waves each
#define NTHR   1024
#define KHALF  1024          // k rows per wave (half range)
#define KPH    128           // k rows staged per phase per stream
#define NPH    (KHALF / KPH) // 8 phases
#define NST    (KPH / 16)    // 8 MFMA steps per phase

typedef __bf16 bf16x8 __attribute__((ext_vector_type(8)));
typedef float  f32x4  __attribute__((ext_vector_type(4)));
typedef float  f32x8  __attribute__((ext_vector_type(8)));

#if __has_builtin(__builtin_amdgcn_exp2f)
#define EXP2F(x) __builtin_amdgcn_exp2f(x)
#else
#define EXP2F(x) exp2f(x)
#endif

__device__ __forceinline__ float gelu_exact(float x) {
    return 0.5f * x * (1.0f + erff(x * 0.70710678118654752f));
}

// ---------------------------------------------------------------------------
// v9: FAT WAVES x 4 WAVES/SIMD via in-block split-K.
// Ledger r1-r8: dur ~= stats-VALU-work (~17-22us) / VALUBusy; VALUBusy
// pinned ~20% at 2 waves/SIMD (r8, fat) and at 16 thin waves/CU (r7).
// Fat waves (32 q/wave, r8's +19%) cap at 8 waves/CU unless waves split k.
// v9: 1024-thr blocks, 16 waves: wave w = q-group (w>>1, 32 rows) x k-half
// (w&1, 1024 rows).  Grid (32 bh, 8 qb) = 256 blocks = 1/CU, 4 waves/SIMD,
// VGPR hard-capped at 128 by the 1024-thr block (no r3/r4 balloon).
// Two 128-row K streams (one per k-half) staged bf16 double-buffered
// (4 x 16 KB), T2 XOR-swizzle (r7/r8: 0 conflicts), T14 issue-early/
// write-late, ONE raw s_barrier per phase (7 total), vmcnt never drained.
// Per-row stats (m=max s', Z=sum 2^s', Z2=sum 2^2s', sm=sum s'; log2
// domain, Q pre-scaled by (1/8)*log2e) combine across the two k-halves
// IN-BLOCK via an 8 KB LDS partial table: Z/Z2/sm add, m fmax, then
// per-row var=(Z2/Z^2-1/n)/(n-1); sum/max restored by *ln2 at the end.
// Last block (atomic counter) runs the 3->64->64->1 GELU MLP head.
// ---------------------------------------------------------------------------
__global__ __launch_bounds__(NTHR) void fused_attn_stats_mlp(
    const float* __restrict__ Q, const float* __restrict__ K,
    const float* __restrict__ W1, const float* __restrict__ b1,
    const float* __restrict__ W2, const float* __restrict__ b2,
    const float* __restrict__ W3, const float* __restrict__ b3,
    float* __restrict__ ws, float* __restrict__ out)
{
    // [ kh0: parity0 16KB | kh0: parity1 16KB | kh1: parity0 | kh1: parity1 ]
    __shared__ __align__(16) unsigned char smem[64 * 1024];

    const int t    = threadIdx.x;
    const int lane = t & 63;
    const int w    = t >> 6;        // wave 0..15
    const int qg   = w >> 1;        // q-group 0..7 -> rows [qg*32, +32)
    const int kh   = w & 1;         // k-half 0/1 -> rows [kh*1024, +1024)
    const int lrow = lane & 15;     // fragment row index
    const int lq   = lane >> 4;     // quad: d = lq*8 + j
    const int bh   = blockIdx.x;
    const int qb   = blockIdx.y;

    // ---- Q loads first (vmcnt in-order: A-cvt waits only on Q) ----
    const float SC = 0.18033688011112042592f;      // (1/sqrt(64)) * log2(e)
    const float* qrow = Q + ((size_t)bh * S + (size_t)qb * QBLK + qg * 32 + lrow) * DK;
    f32x8 qa = *(const f32x8*)(qrow + lq * 8);
    f32x8 qv = *(const f32x8*)(qrow + 32 + lq * 8);
    f32x8 qc = *(const f32x8*)(qrow + 16 * DK + lq * 8);
    f32x8 qd = *(const f32x8*)(qrow + 16 * DK + 32 + lq * 8);

    // ---- staging ownership: thread handles 16 floats of ONE stream ----
    const int n    = t & 511;       // 0..511 within the stream's thread set
    const int sidx = t >> 9;        // which stream this thread stages
    const float* gK = K + (size_t)bh * S * DK + (size_t)sidx * KHALF * DK + (size_t)n * 16;
    char* myBuf = (char*)smem + sidx * 32768;
    const int wrow  = n >> 2;                         // buffer-local row
    const int wc8   = (n & 3) * 2;                    // first 16B group
    const int wbyte = wrow * 128 + ((wc8 ^ (wrow & 7)) << 4);

    f32x4 s0, s1, s2, s3;           // 16 persistent staging VGPRs
#define ISSUE(p) { const float* _gp = gK + (size_t)(p) * (KPH * DK);       \
        s0 = *(const f32x4*)(_gp);      s1 = *(const f32x4*)(_gp + 4);     \
        s2 = *(const f32x4*)(_gp + 8);  s3 = *(const f32x4*)(_gp + 12); }

#define WRITE(par) { char* _d = myBuf + (par) * 16384;                     \
        f32x8 _a = __builtin_shufflevector(s0, s1, 0, 1, 2, 3, 4, 5, 6, 7);\
        f32x8 _b = __builtin_shufflevector(s2, s3, 0, 1, 2, 3, 4, 5, 6, 7);\
        *(bf16x8*)(_d + wbyte)        = __builtin_convertvector(_a, bf16x8);\
        *(bf16x8*)(_d + (wbyte ^ 16)) = __builtin_convertvector(_b, bf16x8); }

#define PIPE_BAR() {                                                       \
        asm volatile("s_waitcnt lgkmcnt(0)" ::: "memory");                 \
        __builtin_amdgcn_s_barrier();                                      \
        asm volatile("" ::: "memory"); }

    // ---- prologue ----
    ISSUE(0);
    const bf16x8 a0_lo = __builtin_convertvector(qa * SC, bf16x8);
    const bf16x8 a0_hi = __builtin_convertvector(qv * SC, bf16x8);
    const bf16x8 a1_lo = __builtin_convertvector(qc * SC, bf16x8);
    const bf16x8 a1_hi = __builtin_convertvector(qd * SC, bf16x8);
    WRITE(0);                       // waits phase-0 vmcnt only
    __syncthreads();                // both streams' parity-0 buffers visible

    float m[8], Zs[8], Z2[8], sm[8];   // u = f*4+i -> row qg*32 + f*16 + lq*4 + i
#pragma unroll
    for (int u = 0; u < 8; ++u) { m[u] = -INFINITY; Zs[u] = 0.f; Z2[u] = 0.f; sm[u] = 0.f; }

    const int obase = lrow * 128 + ((lq ^ (lrow & 7)) << 4);
    const char* rdBase = (const char*)smem + kh * 32768;

    for (int p = 0; p < NPH; ++p) {
        if (p + 1 < NPH) ISSUE(p + 1);          // in flight across the phase
        const char* HB = rdBase + (p & 1) * 16384;
#pragma unroll 4
        for (int j = 0; j < NST; ++j) {
            const int off = j * 2048 + obase;
            const bf16x8 b_lo = *(const bf16x8*)(HB + off);
            const bf16x8 b_hi = *(const bf16x8*)(HB + (off ^ 64));
            f32x4 ac0 = {0.f, 0.f, 0.f, 0.f};
            f32x4 ac1 = {0.f, 0.f, 0.f, 0.f};
            ac0 = __builtin_amdgcn_mfma_f32_16x16x32_bf16(a0_lo, b_lo, ac0, 0, 0, 0);
            ac0 = __builtin_amdgcn_mfma_f32_16x16x32_bf16(a0_hi, b_hi, ac0, 0, 0, 0);
            ac1 = __builtin_amdgcn_mfma_f32_16x16x32_bf16(a1_lo, b_lo, ac1, 0, 0, 0);
            ac1 = __builtin_amdgcn_mfma_f32_16x16x32_bf16(a1_hi, b_hi, ac1, 0, 0, 0);
#pragma unroll
            for (int i = 0; i < 4; ++i) {
                const float v0 = ac0[i], v1 = ac1[i];
                const float p0 = EXP2F(v0), p1 = EXP2F(v1);
                m[i]      = fmaxf(m[i], v0);      m[4 + i]  = fmaxf(m[4 + i], v1);
                Zs[i]    += p0;                   Zs[4 + i] += p1;
                Z2[i]     = fmaf(p0, p0, Z2[i]);
                Z2[4 + i] = fmaf(p1, p1, Z2[4 + i]);
                sm[i]    += v0;                   sm[4 + i] += v1;
            }
        }
        if (p + 1 < NPH) {
            WRITE((p + 1) & 1);                 // vmcnt wait: one phase old
            PIPE_BAR();                         // buffer ready; vmcnt NOT drained
        }
        // after the phase-6 barrier all waves are in phase 7 (reads parity 1
        // only), so the parity-0 region below is safe to reuse post-loop.
    }

    // ---- reduce across the 16 col-lanes, publish per-row partials ----
#pragma unroll
    for (int off = 1; off < 16; off <<= 1) {
#pragma unroll
        for (int u = 0; u < 8; ++u) {
            m[u]   = fmaxf(m[u], __shfl_xor(m[u], off, 64));
            Zs[u] += __shfl_xor(Zs[u], off, 64);
            Z2[u] += __shfl_xor(Z2[u], off, 64);
            sm[u] += __shfl_xor(sm[u], off, 64);
        }
    }
    float4* part  = (float4*)smem;              // part[kh*256 + row], 8 KB
    float*  red   = (float*)(smem + 8192);      // 3 floats
    int*    lastF = (int*)(smem + 8204);
    if (lrow == 0) {
#pragma unroll
        for (int u = 0; u < 8; ++u) {
            const int R = qg * 32 + (u >> 2) * 16 + lq * 4 + (u & 3);
            part[kh * 256 + R] = make_float4(m[u], Zs[u], Z2[u], sm[u]);
        }
    }
    if (t < 3) red[t] = 0.0f;
    __syncthreads();

    // ---- combine k-halves per row, block-reduce the 3 features ----
    {
        float psum = 0.f, pmax = 0.f, pvar = 0.f;
        if (t < 256) {
            const float4 A = part[t];
            const float4 B = part[256 + t];
            const float Z  = A.y + B.y;
            const float iz = 1.0f / Z;
            pmax = fmaxf(A.x, B.x);
            psum = A.w + B.w;
            pvar = ((A.z + B.z) * iz * iz - (1.0f / 2048.0f)) * (1.0f / 2047.0f);
        }
#pragma unroll
        for (int off = 1; off < 64; off <<= 1) {
            psum += __shfl_xor(psum, off, 64);
            pmax += __shfl_xor(pmax, off, 64);
            pvar += __shfl_xor(pvar, off, 64);
        }
        if (lane == 0 && w < 4) {
            atomicAdd(&red[0], psum);
            atomicAdd(&red[1], pmax);
            atomicAdd(&red[2], pvar);
        }
    }
    __syncthreads();
    if (t == 0) {
        const float LN2 = 0.69314718055994530942f;
        atomicAdd(&ws[bh * 3 + 0], red[0] * LN2);   // back to natural-log domain
        atomicAdd(&ws[bh * 3 + 1], red[1] * LN2);
        atomicAdd(&ws[bh * 3 + 2], red[2]);
        __threadfence();
        const int old = atomicAdd((int*)(ws + 96), 1);
        *lastF = (old == NBLK - 1);
    }
    __syncthreads();
    if (!*lastF) return;

    // =========================== MLP head (last block) ======================
    float* H1    = (float*)(smem + 8256);   // 32*65 floats
    float* featL = H1 + 32 * 65;            // 96 floats
    float* logtL = featL + 96;              // 32 floats

    if (t < 96)               featL[t] = atomicAdd(&ws[t], 0.0f); // coherent read
    if (t >= 96 && t < 128)   logtL[t - 96] = 0.0f;
    __syncthreads();

    if (t < 64) {
        const float w1a = W1[t], w1b = W1[64 + t], w1c = W1[128 + t], bb1 = b1[t];
        for (int b = 0; b < 32; ++b) {
            const float f0 = featL[b * 3 + 0] * (1.0f / ((float)S * (float)S));
            const float f1 = featL[b * 3 + 1] * (1.0f / (float)S);
            const float f2 = featL[b * 3 + 2] * (1.0f / (float)S);
            H1[b * 65 + t] = gelu_exact(f0 * w1a + f1 * w1b + f2 * w1c + bb1);
        }
    }
    __syncthreads();
    if (t < 512) {
        // threads 0..511: 16 threads per bh, 4 hidden-2 units each
        const int b = t >> 4, jb = (t & 15) * 4;
        float a0 = 0.f, a1 = 0.f, a2 = 0.f, a3 = 0.f;
        for (int k = 0; k < 64; ++k) {
            const float hk = H1[b * 65 + k];
            const float4 wa = *(const float4*)&W2[k * 64 + jb];
            a0 += hk * wa.x; a1 += hk * wa.y; a2 += hk * wa.z; a3 += hk * wa.w;
        }
        const float partl = gelu_exact(a0 + b2[jb + 0]) * W3[jb + 0]
                          + gelu_exact(a1 + b2[jb + 1]) * W3[jb + 1]
                          + gelu_exact(a2 + b2[jb + 2]) * W3[jb + 2]
                          + gelu_exact(a3 + b2[jb + 3]) * W3[jb + 3];
        atomicAdd(&logtL[b], partl);
    }
    __syncthreads();
    if (t < 32) {
        float lt = logtL[t] + b3[0];
        lt = fminf(fmaxf(lt, -2.3025850929940457f), 2.3025850929940457f);
        out[t] = expf(lt);
    }
}

// ---------------------------------------------------------------------------
extern "C" void kernel_launch(void* const* d_in, const int* in_sizes, int n_in,
                              void* d_out, int out_size, void* d_ws, size_t ws_size,
                              hipStream_t stream)
{
    const float* Q  = (const float*)d_in[0];
    const float* K  = (const float*)d_in[1];
    const float* W1 = (const float*)d_in[2];
    const float* b1 = (const float*)d_in[3];
    const float* W2 = (const float*)d_in[4];
    const float* b2 = (const float*)d_in[5];
    const float* W3 = (const float*)d_in[6];
    const float* b3 = (const float*)d_in[7];
    float* out = (float*)d_out;
    float* ws  = (float*)d_ws;

    // zero the 96 stat accumulators + the int block counter at ws[96]
    hipMemsetAsync(ws, 0, 512, stream);

    dim3 grid(NBH, NQB);   // bh fastest -> each bh's K pinned to one XCD L2
    fused_attn_stats_mlp<<<grid, NTHR, 0, stream>>>(Q, K, W1, b1, W2, b2, W3, b3, ws, out);
}